// Round 10
// baseline (187.532 us; speedup 1.0000x reference)
//
#include <hip/hip_runtime.h>
#include <hip/hip_bf16.h>

// Problem constants
#define VV 200000
#define DD 512
#define NN 32768
#define RR 8
#define HH 16
#define CLAMPV 1000.0f

typedef __attribute__((ext_vector_type(8))) short short8;
typedef __attribute__((ext_vector_type(4))) float f32x4;
typedef __attribute__((ext_vector_type(4))) unsigned int u32x4;

__device__ __forceinline__ unsigned f2bf(float f) {
  union { float f; unsigned u; } v; v.f = f;
  return (v.u + 0x7FFFu + ((v.u >> 16) & 1u)) >> 16;   // RNE f32->bf16
}
__device__ __forceinline__ unsigned pack2(float lo, float hi) {
  return f2bf(lo) | (f2bf(hi) << 16);
}

// ---------------- prep 1: addvec[d] = clip(phase(t))[d] + err[d] -------------
__global__ void prep_phase_k(const float* __restrict__ base_phase,
                             const float* __restrict__ amp,
                             const float* __restrict__ freq,
                             const float* __restrict__ poff,
                             const float* __restrict__ err,
                             const int* __restrict__ tstep,
                             float* __restrict__ addvec) {
  const int d = threadIdx.x;          // 512 threads
  const float t = (float)(*tstep);
  float s = base_phase[d];
#pragma unroll
  for (int h = 0; h < HH; ++h)
    s += amp[h * DD + d] * sinf(freq[h] * t + poff[h]);
  s = fminf(fmaxf(s, -CLAMPV), CLAMPV);
  addvec[d] = s + err[d];
}

// ------------- prep 2: B in MFMA fragment-image layout -----------------------
__global__ void prep_bt_k(const float* __restrict__ transform,
                          const float* __restrict__ cw,
                          unsigned short* __restrict__ bt) {
  const int bid = blockIdx.x;                    // 1024 blocks x 256 threads
  const int s = bid >> 3;                        // 0..127
  const int g = ((bid & 7) << 2) + (threadIdx.x >> 6);  // 0..31
  const int l = threadIdx.x & 63;
  const int e = g * 16 + (l & 15);
  const int k0 = s * 32 + ((l >> 4) << 3);
  const float scale = cw[s >> 4];                // r = (s*32)/512, uniform
  u32x4 w;
#pragma unroll
  for (int p = 0; p < 4; ++p) {
    const float lo = transform[(size_t)(k0 + 2 * p) * DD + e] * scale;
    const float hi = transform[(size_t)(k0 + 2 * p + 1) * DD + e] * scale;
    w[p] = pack2(lo, hi);
  }
  *(u32x4*)(bt + (((size_t)s * 32 + g) * 64 + l) * 8) = w;
}

// ----------------------------- main fused GEMM -------------------------------
// C[32768x512] = gatherA[32768x4096] x B[4096x512] (+ base + addvec, clamp).
// BM=64, BN=512, 512 blocks (1/CU), 8 waves, wave = 64x64 (4x4 frags).
// FULL-ROW gather: per step each WAVE reads one full 2KB codebook row for the
// NEXT 8-kt phase (2x dwordx4/lane, one contiguous DRAM burst), scattered to
// 8 per-kt LDS slots (R1's proven swizzle; each lane -> one slot). Two whole
// phase buffers (2 x 64KB) so next-phase writes never touch the buffer being
// read. Consumers: R3's proven slot reads + B-fragment reg dbuf (L2-resident
// fragment-image ws). Counted vmcnt per step; barrier-free final phase.
#define VM_WAIT(N) asm volatile("s_waitcnt vmcnt(" #N ")" ::: "memory")
#define LGKM0()    asm volatile("s_waitcnt lgkmcnt(0)" ::: "memory")
#define BARRIER()  __builtin_amdgcn_s_barrier()

#define LOADB(DST, KT)                                                        \
  {                                                                           \
    const unsigned short* b0_ =                                               \
        bt + (size_t)(KT) * 32768 + wv * 2048 + lane * 8;                     \
    _Pragma("unroll") for (int n = 0; n < 4; ++n) {                           \
      DST[n][0] = *(const short8*)(b0_ + n * 512);                            \
      DST[n][1] = *(const short8*)(b0_ + 16384 + n * 512);                    \
    }                                                                         \
  }

// issue full-row load of row G*8+wv (ref r=RP1) into SET{0,1}
#define PISSUE(S0, S1, G, RP1)                                                \
  {                                                                           \
    const int ri_ = refs_lds[((G) * 8 + wv) * 8 + (RP1)];                     \
    const float* s_ = codebook + (size_t)ri_ * DD + (lane << 3);              \
    S0 = *(const f32x4*)(s_);                                                 \
    S1 = *(const f32x4*)(s_ + 4);                                             \
  }

// write row G*8+wv into BUFN: slice = lane>>3 (slot), chunk = (lane&7)^wv
#define PWRITE(S0, S1, G, BUFN)                                               \
  {                                                                           \
    u32x4 w_;                                                                 \
    w_[0] = pack2(S0[0], S0[1]); w_[1] = pack2(S0[2], S0[3]);                 \
    w_[2] = pack2(S1[0], S1[1]); w_[3] = pack2(S1[2], S1[3]);                 \
    *(u32x4*)((BUFN) + pslice + ((G) * 8 + wv) * 128 + pchunk) = w_;          \
  }

#define CMFMA(BF, SLOTB)                                                      \
  {                                                                           \
    __builtin_amdgcn_s_setprio(1);                                            \
    _Pragma("unroll") for (int ks = 0; ks < 2; ++ks) {                        \
      _Pragma("unroll") for (int m = 0; m < 4; ++m) {                         \
        const short8 aFv = *(const short8*)((SLOTB) + m * 2048 + rbase +      \
                                            ((ks * 64 + koff) ^ rsw));        \
        _Pragma("unroll") for (int n = 0; n < 4; ++n)                         \
          acc[m][n] = __builtin_amdgcn_mfma_f32_16x16x32_bf16(                \
              aFv, (BF)[n][ks], acc[m][n], 0, 0, 0);                          \
      }                                                                       \
    }                                                                         \
    __builtin_amdgcn_s_setprio(0);                                            \
  }

// steady phase P (0..6): compute kts P*8..P*8+7 from BUFC, stage phase P+1
// into BUFN. Entry queue invariant: [B(P*8): 8 loads]. Exit: [B(P*8+8): 8].
#define PHASE_STEADY(P)                                                       \
  {                                                                           \
    char* bufc = lds_a + ((P) & 1) * 65536;                                   \
    char* bufn = lds_a + (((P) + 1) & 1) * 65536;                             \
    /* j=0 */                                                                 \
    LOADB(bF1, (P)*8 + 1); PISSUE(pa0, pa1, 0, (P) + 1);                      \
    VM_WAIT(10); CMFMA(bF0, bufc); LGKM0(); BARRIER();                        \
    /* j=1 */                                                                 \
    LOADB(bF0, (P)*8 + 2); PISSUE(pb0, pb1, 1, (P) + 1);                      \
    VM_WAIT(10); PWRITE(pa0, pa1, 0, bufn);                                   \
    CMFMA(bF1, bufc + 8192); LGKM0(); BARRIER();                              \
    /* j=2 */                                                                 \
    LOADB(bF1, (P)*8 + 3); PISSUE(pa0, pa1, 2, (P) + 1);                      \
    VM_WAIT(10); PWRITE(pb0, pb1, 1, bufn);                                   \
    CMFMA(bF0, bufc + 2 * 8192); LGKM0(); BARRIER();                          \
    /* j=3 */                                                                 \
    LOADB(bF0, (P)*8 + 4); PISSUE(pb0, pb1, 3, (P) + 1);                      \
    VM_WAIT(10); PWRITE(pa0, pa1, 2, bufn);                                   \
    CMFMA(bF1, bufc + 3 * 8192); LGKM0(); BARRIER();                          \
    /* j=4 */                                                                 \
    LOADB(bF1, (P)*8 + 5); PISSUE(pa0, pa1, 4, (P) + 1);                      \
    VM_WAIT(10); PWRITE(pb0, pb1, 3, bufn);                                   \
    CMFMA(bF0, bufc + 4 * 8192); LGKM0(); BARRIER();                          \
    /* j=5 */                                                                 \
    LOADB(bF0, (P)*8 + 6); PISSUE(pb0, pb1, 5, (P) + 1);                      \
    VM_WAIT(10); PWRITE(pa0, pa1, 4, bufn);                                   \
    CMFMA(bF1, bufc + 5 * 8192); LGKM0(); BARRIER();                          \
    /* j=6: retire g5, issue g6 and g7 */                                     \
    LOADB(bF1, (P)*8 + 7); PISSUE(pa0, pa1, 6, (P) + 1);                      \
    VM_WAIT(10); PWRITE(pb0, pb1, 5, bufn); PISSUE(pb0, pb1, 7, (P) + 1);     \
    CMFMA(bF0, bufc + 6 * 8192); LGKM0(); BARRIER();                          \
    /* j=7: retire B(kt7)+g6+g7, write both */                                \
    LOADB(bF0, (P)*8 + 8);                                                    \
    VM_WAIT(8); PWRITE(pa0, pa1, 6, bufn); PWRITE(pb0, pb1, 7, bufn);         \
    CMFMA(bF1, bufc + 7 * 8192); LGKM0(); BARRIER();                          \
  }

__global__ __launch_bounds__(512, 2)
void rw_gemm_k(const float* __restrict__ codebook,
               const int* __restrict__ base_idx,
               const int* __restrict__ ref_idx,
               const unsigned short* __restrict__ bt,
               const float* __restrict__ addvec,
               float* __restrict__ out) {
  __shared__ char lds_a[2 * 65536];              // 2 phase-bufs x 8 slots x 8KB
  __shared__ int refs_lds[512];                  // 64 rows x 8 refs

  const int tid = threadIdx.x;                   // 512 threads = 8 waves
  const int lane = tid & 63;
  const int wv = tid >> 6;                       // 0..7
  const int mb = blockIdx.x;                     // rows mb*64 .. +63

  const f32x4 zero = {0.f, 0.f, 0.f, 0.f};
  f32x4 acc[4][4];
#pragma unroll
  for (int m = 0; m < 4; ++m)
#pragma unroll
    for (int n = 0; n < 4; ++n)
      acc[m][n] = zero;

  // producer constants: wave stages row g*8+wv; (row&7)==wv
  const int pslice = (lane >> 3) * 8192;
  const int pchunk = ((lane & 7) ^ wv) * 16;
  // consumer fragment-read constants (R1 zero-conflict)
  const int rsw = (lane & 7) << 4;
  const int rbase = (lane & 15) * 128;
  const int koff = (lane >> 4) * 16;

  short8 bF0[4][2], bF1[4][2];
  f32x4 pa0, pa1, pb0, pb1;

  // ---- prologue: refs -> LDS; stage full phase 0 (r=0) into buf0 ----
  refs_lds[tid] = ref_idx[(size_t)mb * 512 + tid];   // coalesced 2KB
  __syncthreads();
#pragma unroll
  for (int gg = 0; gg < 8; gg += 2) {
    PISSUE(pa0, pa1, gg, 0); PISSUE(pb0, pb1, gg + 1, 0);
    VM_WAIT(0);
    PWRITE(pa0, pa1, gg, lds_a); PWRITE(pb0, pb1, gg + 1, lds_a);
  }
  __syncthreads();                               // phase-0 visible, vmcnt=0
  LOADB(bF0, 0);                                 // entry queue = [B(0): 8]

  // ---- steady phases 0..6 ----
  PHASE_STEADY(0) PHASE_STEADY(1) PHASE_STEADY(2) PHASE_STEADY(3)
  PHASE_STEADY(4) PHASE_STEADY(5) PHASE_STEADY(6)

  // ---- final phase 7 (kts 56..63) from buf1: no staging, no barriers ----
  {
    char* bufc = lds_a + 65536;
    LOADB(bF1, 57); VM_WAIT(8); CMFMA(bF0, bufc);
    LOADB(bF0, 58); VM_WAIT(8); CMFMA(bF1, bufc + 8192);
    LOADB(bF1, 59); VM_WAIT(8); CMFMA(bF0, bufc + 2 * 8192);
    LOADB(bF0, 60); VM_WAIT(8); CMFMA(bF1, bufc + 3 * 8192);
    LOADB(bF1, 61); VM_WAIT(8); CMFMA(bF0, bufc + 4 * 8192);
    LOADB(bF0, 62); VM_WAIT(8); CMFMA(bF1, bufc + 5 * 8192);
    LOADB(bF1, 63); VM_WAIT(8); CMFMA(bF0, bufc + 6 * 8192);
    VM_WAIT(0);                 CMFMA(bF1, bufc + 7 * 8192);
  }

  // epilogue: + base gather + addvec, clamp, store f32
  // C/D layout: col = lane&15, row = (lane>>4)*4 + reg
#pragma unroll
  for (int m = 0; m < 4; ++m) {
#pragma unroll
    for (int j = 0; j < 4; ++j) {
      const int row = mb * 64 + m * 16 + ((lane >> 4) << 2) + j;
      const int bi = base_idx[row];
      const float* brow = codebook + (size_t)bi * DD;
#pragma unroll
      for (int n = 0; n < 4; ++n) {
        const int col = wv * 64 + n * 16 + (lane & 15);
        float v = acc[m][n][j] + brow[col] + addvec[col];
        v = fminf(fmaxf(v, -CLAMPV), CLAMPV);
        out[(size_t)row * DD + col] = v;
      }
    }
  }
}

extern "C" void kernel_launch(void* const* d_in, const int* in_sizes, int n_in,
                              void* d_out, int out_size, void* d_ws, size_t ws_size,
                              hipStream_t stream) {
  const float* codebook   = (const float*)d_in[0];
  const int*   base_idx   = (const int*)d_in[1];
  const int*   ref_idx    = (const int*)d_in[2];
  const float* transform  = (const float*)d_in[3];
  const float* contrib_w  = (const float*)d_in[4];
  const float* base_phase = (const float*)d_in[5];
  const float* amp        = (const float*)d_in[6];
  const float* freq       = (const float*)d_in[7];
  const float* poff       = (const float*)d_in[8];
  const float* err        = (const float*)d_in[9];
  const int*   tstep      = (const int*)d_in[10];
  float* out = (float*)d_out;

  // ws layout: [0,2048) addvec f32[512]; [2048, 2048+4MB) B fragment-image bf16
  float* addvec = (float*)d_ws;
  unsigned short* bt = (unsigned short*)((char*)d_ws + 2048);

  prep_phase_k<<<1, 512, 0, stream>>>(base_phase, amp, freq, poff, err, tstep, addvec);
  prep_bt_k<<<1024, 256, 0, stream>>>(transform, contrib_w, bt);
  rw_gemm_k<<<512, 512, 0, stream>>>(codebook, base_idx, ref_idx, bt, addvec, out);
}

// Round 11
// 165.674 us; speedup vs baseline: 1.1319x; 1.1319x over previous
//
#include <hip/hip_runtime.h>
#include <hip/hip_bf16.h>

// Problem constants
#define VV 200000
#define DD 512
#define NN 32768
#define RR 8
#define HH 16
#define CLAMPV 1000.0f

typedef __attribute__((ext_vector_type(8))) short short8;
typedef __attribute__((ext_vector_type(4))) float f32x4;
typedef __attribute__((ext_vector_type(4))) unsigned int u32x4;

__device__ __forceinline__ unsigned f2bf(float f) {
  union { float f; unsigned u; } v; v.f = f;
  return (v.u + 0x7FFFu + ((v.u >> 16) & 1u)) >> 16;   // RNE f32->bf16
}
__device__ __forceinline__ unsigned pack2(float lo, float hi) {
  return f2bf(lo) | (f2bf(hi) << 16);
}

// ---------------- prep 1: addvec[d] = clip(phase(t))[d] + err[d] -------------
__global__ void prep_phase_k(const float* __restrict__ base_phase,
                             const float* __restrict__ amp,
                             const float* __restrict__ freq,
                             const float* __restrict__ poff,
                             const float* __restrict__ err,
                             const int* __restrict__ tstep,
                             float* __restrict__ addvec) {
  const int d = threadIdx.x;          // 512 threads
  const float t = (float)(*tstep);
  float s = base_phase[d];
#pragma unroll
  for (int h = 0; h < HH; ++h)
    s += amp[h * DD + d] * sinf(freq[h] * t + poff[h]);
  s = fminf(fmaxf(s, -CLAMPV), CLAMPV);
  addvec[d] = s + err[d];
}

// ------------- prep 2: B in MFMA fragment-image layout -----------------------
// bt[((s*32 + g)*64 + l)*8 + j] = bf16( transform[k][e] * w[k/512] )
//   s = k32-slice (0..127), g = e-group (0..31), e = g*16 + (l&15),
//   k = s*32 + (l>>4)*8 + j  — the verified 16x16x32 B-fragment lane mapping.
__global__ void prep_bt_k(const float* __restrict__ transform,
                          const float* __restrict__ cw,
                          unsigned short* __restrict__ bt) {
  const int bid = blockIdx.x;                    // 1024 blocks x 256 threads
  const int s = bid >> 3;                        // 0..127
  const int g = ((bid & 7) << 2) + (threadIdx.x >> 6);  // 0..31
  const int l = threadIdx.x & 63;
  const int e = g * 16 + (l & 15);
  const int k0 = s * 32 + ((l >> 4) << 3);
  const float scale = cw[s >> 4];                // r = (s*32)/512, uniform
  u32x4 w;
#pragma unroll
  for (int p = 0; p < 4; ++p) {
    const float lo = transform[(size_t)(k0 + 2 * p) * DD + e] * scale;
    const float hi = transform[(size_t)(k0 + 2 * p + 1) * DD + e] * scale;
    w[p] = pack2(lo, hi);
  }
  *(u32x4*)(bt + (((size_t)s * 32 + g) * 64 + l) * 8) = w;
}

// ----------------------------- main fused GEMM -------------------------------
// R3's best-known structure (168 us total) + ONE fix: refs preloaded into LDS
// so the per-8-kt ref fetch is a ds_read instead of a global load whose
// address-dependent use forced a full vmcnt queue drain (FIFO semantics).
// BM=128, BN=512, BK=64, 256 blocks (1/CU), 8 waves, wave = 128x64 (8x4).
// Counted-vmcnt pipeline: A-gather 2 kt deep (reg-staged, f32->bf16->LDS dbuf,
// XOR-swizzled), B fragments 1 kt deep (reg dbuf, straight from L2-resident
// fragment-image ws). Raw s_barrier (no vmcnt drain) once per kt.
#define VM_WAIT(N) asm volatile("s_waitcnt vmcnt(" #N ")" ::: "memory")
#define LGKM0()    asm volatile("s_waitcnt lgkmcnt(0)" ::: "memory")

#define GSTEP(KT, ASC, ASN, BFC, BFN, ABR, ABW, VMN, DOA, DOB, DOBAR)         \
  {                                                                           \
    if (DOB) { /* B(KT+1) -> BFN, 8x coalesced 1KB dwordx4 */                 \
      const unsigned short* b0 =                                              \
          bt + (size_t)((KT) + 1) * 32768 + wv * 2048 + lane * 8;             \
      _Pragma("unroll") for (int n = 0; n < 4; ++n) {                         \
        BFN[n][0] = *(const short8*)(b0 + n * 512);                           \
        BFN[n][1] = *(const short8*)(b0 + 16384 + n * 512);                   \
      }                                                                       \
    }                                                                         \
    if (DOA) { /* A-gather(KT+2) -> ASN (f32, 16 floats/thread) */            \
      const int kt2 = (KT) + 2;                                               \
      if ((kt2 & 7) == 0) ridx = refs_lds[arow * 8 + (kt2 >> 3)];             \
      const float* asrc =                                                     \
          codebook + (size_t)ridx * DD + ((kt2 & 7) << 6) + aq * 16;          \
      ASN[0] = *(const f32x4*)(asrc);                                         \
      ASN[1] = *(const f32x4*)(asrc + 4);                                     \
      ASN[2] = *(const f32x4*)(asrc + 8);                                     \
      ASN[3] = *(const f32x4*)(asrc + 12);                                    \
    }                                                                         \
    VM_WAIT(VMN); /* retires A(KT+1) + B(KT); newer stay in flight */         \
    if ((KT) < 63) { /* convert + ds_write A(KT+1) -> ABW */                  \
      u32x4 w0, w1;                                                           \
      w0[0] = pack2(ASC[0][0], ASC[0][1]); w0[1] = pack2(ASC[0][2], ASC[0][3]);\
      w0[2] = pack2(ASC[1][0], ASC[1][1]); w0[3] = pack2(ASC[1][2], ASC[1][3]);\
      w1[0] = pack2(ASC[2][0], ASC[2][1]); w1[1] = pack2(ASC[2][2], ASC[2][3]);\
      w1[2] = pack2(ASC[3][0], ASC[3][1]); w1[3] = pack2(ASC[3][2], ASC[3][3]);\
      *(u32x4*)((ABW) + wbyte0) = w0;                                         \
      *(u32x4*)((ABW) + wbyte1) = w1;                                         \
    }                                                                         \
    __builtin_amdgcn_s_setprio(1);                                            \
    _Pragma("unroll") for (int ks = 0; ks < 2; ++ks) {                        \
      _Pragma("unroll") for (int m = 0; m < 8; ++m) {                         \
        const short8 aFv = *(const short8*)((ABR) + m * 2048 + rbase          \
                                            + ((ks * 64 + koff) ^ rsw));      \
        _Pragma("unroll") for (int n = 0; n < 4; ++n)                         \
          acc[m][n] = __builtin_amdgcn_mfma_f32_16x16x32_bf16(                \
              aFv, BFC[n][ks], acc[m][n], 0, 0, 0);                           \
      }                                                                       \
    }                                                                         \
    __builtin_amdgcn_s_setprio(0);                                            \
    if (DOBAR) { LGKM0(); __builtin_amdgcn_s_barrier(); }                     \
  }

__global__ __launch_bounds__(512, 2)
void rw_gemm_k(const float* __restrict__ codebook,
               const int* __restrict__ base_idx,
               const int* __restrict__ ref_idx,
               const unsigned short* __restrict__ bt,
               const float* __restrict__ addvec,
               float* __restrict__ out) {
  __shared__ unsigned short aT[2][128 * 64];     // 16 KB x2, swizzled [row][k]
  __shared__ int refs_lds[1024];                 // 128 rows x 8 refs

  const int tid = threadIdx.x;
  const int lane = tid & 63;
  const int wv = tid >> 6;                       // 0..7 -> col block (64 cols)
  const int mb = blockIdx.x;                     // rows mb*128 .. +127

  const f32x4 zero = {0.f, 0.f, 0.f, 0.f};
  f32x4 acc[8][4];
#pragma unroll
  for (int m = 0; m < 8; ++m)
#pragma unroll
    for (int n = 0; n < 4; ++n)
      acc[m][n] = zero;

  // A staging map: thread -> (row = tid/4, 16 f32 at chunks 2*(tid&3),+1)
  const int arow = tid >> 2;
  const int aq = tid & 3;
  const unsigned sw = (arow & 7) << 4;
  char* ab0 = (char*)&aT[0][0];
  char* ab1 = (char*)&aT[1][0];
  const int wbyte0 = arow * 128 + (((aq * 2) * 16) ^ sw);
  const int wbyte1 = arow * 128 + (((aq * 2) * 16 + 16) ^ sw);

  // fragment-read constants: row = m*16 + (lane&15); row&7 == lane&7
  const unsigned rsw = (lane & 7) << 4;
  const int rbase = (lane & 15) * 128;
  const int koff = (lane >> 4) * 16;

  // ---- refs -> LDS (removes the mid-loop address-dependent global load) ----
  refs_lds[tid] = ref_idx[(size_t)mb * 1024 + tid];
  refs_lds[512 + tid] = ref_idx[(size_t)mb * 1024 + 512 + tid];
  __syncthreads();
  int ridx = refs_lds[arow * 8];

  f32x4 as0[4], as1[4];
  short8 bF0[4][2], bF1[4][2];

  // ---- prologue: A(0)->LDS buf0, B(0)->bF0, A(1)->as1, one full drain ----
  {
    const float* asrc = codebook + (size_t)ridx * DD + aq * 16;
    as0[0] = *(const f32x4*)(asrc);
    as0[1] = *(const f32x4*)(asrc + 4);
    as0[2] = *(const f32x4*)(asrc + 8);
    as0[3] = *(const f32x4*)(asrc + 12);
    u32x4 w0, w1;
    w0[0] = pack2(as0[0][0], as0[0][1]); w0[1] = pack2(as0[0][2], as0[0][3]);
    w0[2] = pack2(as0[1][0], as0[1][1]); w0[3] = pack2(as0[1][2], as0[1][3]);
    w1[0] = pack2(as0[2][0], as0[2][1]); w1[1] = pack2(as0[2][2], as0[2][3]);
    w1[2] = pack2(as0[3][0], as0[3][1]); w1[3] = pack2(as0[3][2], as0[3][3]);
    *(u32x4*)(ab0 + wbyte0) = w0;
    *(u32x4*)(ab0 + wbyte1) = w1;
  }
  {
    const unsigned short* b0 = bt + wv * 2048 + lane * 8;
#pragma unroll
    for (int n = 0; n < 4; ++n) {
      bF0[n][0] = *(const short8*)(b0 + n * 512);
      bF0[n][1] = *(const short8*)(b0 + 16384 + n * 512);
    }
  }
  {
    const float* asrc = codebook + (size_t)ridx * DD + 64 + aq * 16;  // kt=1
    as1[0] = *(const f32x4*)(asrc);
    as1[1] = *(const f32x4*)(asrc + 4);
    as1[2] = *(const f32x4*)(asrc + 8);
    as1[3] = *(const f32x4*)(asrc + 12);
  }
  __syncthreads();   // one-time full drain, acceptable

  // ---- main pipeline: kt = 0..61 steady, 62/63 tail ----
  for (int k2 = 0; k2 < 31; ++k2) {
    const int kt = k2 * 2;
    GSTEP(kt,     as1, as0, bF0, bF1, ab0, ab1, 12, 1, 1, 1);
    GSTEP(kt + 1, as0, as1, bF1, bF0, ab1, ab0, 12, 1, 1, 1);
  }
  GSTEP(62, as1, as0, bF0, bF1, ab0, ab1, 8, 0, 1, 1);
  GSTEP(63, as0, as1, bF1, bF0, ab1, ab0, 0, 0, 0, 0);

  // epilogue: + base gather + addvec, clamp, store f32
  // C/D layout: col = lane&15, row = (lane>>4)*4 + reg
#pragma unroll
  for (int m = 0; m < 8; ++m) {
#pragma unroll
    for (int j = 0; j < 4; ++j) {
      const int row = mb * 128 + m * 16 + ((lane >> 4) << 2) + j;
      const int bi = base_idx[row];
      const float* brow = codebook + (size_t)bi * DD;
#pragma unroll
      for (int n = 0; n < 4; ++n) {
        const int col = wv * 64 + n * 16 + (lane & 15);
        float v = acc[m][n][j] + brow[col] + addvec[col];
        v = fminf(fmaxf(v, -CLAMPV), CLAMPV);
        out[(size_t)row * DD + col] = v;
      }
    }
  }
}

extern "C" void kernel_launch(void* const* d_in, const int* in_sizes, int n_in,
                              void* d_out, int out_size, void* d_ws, size_t ws_size,
                              hipStream_t stream) {
  const float* codebook   = (const float*)d_in[0];
  const int*   base_idx   = (const int*)d_in[1];
  const int*   ref_idx    = (const int*)d_in[2];
  const float* transform  = (const float*)d_in[3];
  const float* contrib_w  = (const float*)d_in[4];
  const float* base_phase = (const float*)d_in[5];
  const float* amp        = (const float*)d_in[6];
  const float* freq       = (const float*)d_in[7];
  const float* poff       = (const float*)d_in[8];
  const float* err        = (const float*)d_in[9];
  const int*   tstep      = (const int*)d_in[10];
  float* out = (float*)d_out;

  // ws layout: [0,2048) addvec f32[512]; [2048, 2048+4MB) B fragment-image bf16
  float* addvec = (float*)d_ws;
  unsigned short* bt = (unsigned short*)((char*)d_ws + 2048);

  prep_phase_k<<<1, 512, 0, stream>>>(base_phase, amp, freq, poff, err, tstep, addvec);
  prep_bt_k<<<1024, 256, 0, stream>>>(transform, contrib_w, bt);
  rw_gemm_k<<<256, 512, 0, stream>>>(codebook, base_idx, ref_idx, bt, addvec, out);
}